// Round 4
// baseline (459.766 us; speedup 1.0000x reference)
//
#include <hip/hip_runtime.h>
#include <math.h>

#define N_RES 1024
#define N_ATOMS 37
#define ATOM_CA 1
#define NBATCH 256
#define BLOCKS 1024           // 4 per batch; 512 threads each (half-residue/thread)
#define SLICES 4              // partial rows per batch
#define NSUM 18
// Round-2/3 lesson: this kernel is miss-concurrency-bound (VALUBusy 1.6%,
// HBM 8%). Scatter loads (12B @ 444B stride) = ~900K line misses; service
// rate scales with resident waves (8 waves/CU -> 100us, 16 -> ~55us). So:
// run at FULL occupancy (32 waves/CU): 1024 blocks x 512 threads, each
// thread loads HALF a residue (even lane: pred triple + mask; odd lane:
// true triple), shfl_xor(1) exchange, odd lanes contribute m=0.
// LDS streaming (round 3) measured 2x WORSE: 2.6x bytes at 0.66 TB/s.
//
// sums layout per partial row:
// 0: M    1-3: Sp    4-6: St    7: Qp    8: Qt    9-17: Cpt[i][j]
// Workspace: float partials[1024][18] (73728 B), then uint ticket (4 B).

// 12-byte triple -> single global_load_dwordx3.
struct F3 { float x, y, z; };

__global__ __launch_bounds__(512, 8) void rmsd_fused_kernel(
    const float* __restrict__ pred, const float* __restrict__ truec,
    const float* __restrict__ mask, float* __restrict__ partials,
    unsigned int* __restrict__ ticket, float* __restrict__ out)
{
    const int blk  = blockIdx.x;        // 0..1023
    const int b    = blk >> 2;          // batch
    const int s    = blk & 3;           // tile-of-256 residues
    const int tid  = threadIdx.x;       // 0..511
    const int role = tid & 1;           // 0: pred+mask, 1: true
    const int n    = s * 256 + (tid >> 1);

    const size_t r = (size_t)b * N_RES + n;
    const float* cp = (role ? truec : pred) + r * (N_ATOMS * 3) + ATOM_CA * 3;

    // Issue both loads immediately; they are the whole kernel.
    const F3 C = *reinterpret_cast<const F3*>(cp);
    float m = 0.0f;
    if (!role) m = mask[r * N_ATOMS + ATOM_CA];   // odd lanes keep m=0

    // Pair exchange: even lane gets partner's true-triple, odd gets pred
    // (odd's values are dead since m=0 there).
    const float o0 = __shfl_xor(C.x, 1, 64);
    const float o1 = __shfl_xor(C.y, 1, 64);
    const float o2 = __shfl_xor(C.z, 1, 64);
    const float p0 = C.x, p1 = C.y, p2 = C.z;     // even: pred (own)
    const float t0 = o0,  t1 = o1,  t2 = o2;      // even: true (partner)

    // ---- per-thread moments (binary mask => m^2 == m; odd lanes all 0) ----
    float acc[NSUM];
    acc[0] = m;
    acc[1] = m * p0;  acc[2] = m * p1;  acc[3] = m * p2;
    acc[4] = m * t0;  acc[5] = m * t1;  acc[6] = m * t2;
    acc[7] = m * (p0*p0 + p1*p1 + p2*p2);
    acc[8] = m * (t0*t0 + t1*t1 + t2*t2);
    acc[9]  = m * p0 * t0; acc[10] = m * p0 * t1; acc[11] = m * p0 * t2;
    acc[12] = m * p1 * t0; acc[13] = m * p1 * t1; acc[14] = m * p1 * t2;
    acc[15] = m * p2 * t0; acc[16] = m * p2 * t1; acc[17] = m * p2 * t2;

    // wave(64) shuffle reduce
#pragma unroll
    for (int k = 0; k < NSUM; ++k) {
        float v = acc[k];
#pragma unroll
        for (int off = 32; off > 0; off >>= 1) v += __shfl_down(v, off, 64);
        acc[k] = v;
    }

    __shared__ float partial[8][NSUM];
    const int wave = tid >> 6, lane = tid & 63;
    if (lane == 0) {
#pragma unroll
        for (int k = 0; k < NSUM; ++k) partial[wave][k] = acc[k];
    }
    __syncthreads();
    if (tid < NSUM) {
        float v = 0.0f;
#pragma unroll
        for (int w = 0; w < 8; ++w) v += partial[w][tid];
        partials[(size_t)blk * NSUM + tid] = v;
    }

    // ---- last-block-done handoff (device-scope, XCD-safe) ----
    __threadfence();
    __syncthreads();
    __shared__ bool amLast;
    if (tid == 0)
        amLast = (atomicAdd(ticket, 1u) == (unsigned)(gridDim.x - 1));
    __syncthreads();
    if (!amLast) return;
    __threadfence();

    // ---- finish: threads 0..255 = batches (256..511 compute dupes, don't
    // store). Theobald QCP, fp64, register-only (dynamic indexing would be
    // demoted to scratch). ----
    {
        const int bb = tid & 255;
        double sm[NSUM];
#pragma unroll
        for (int k = 0; k < NSUM; ++k) sm[k] = 0.0;
#pragma unroll
        for (int k = 0; k < SLICES; ++k) {
            const float* row = partials + ((size_t)bb * SLICES + k) * NSUM;
#pragma unroll
            for (int j = 0; j < NSUM; ++j) sm[j] += (double)row[j];
        }

        const double M   = sm[0];
        const double Mep = M + 1e-8;
        const double Sp0 = sm[1], Sp1 = sm[2], Sp2 = sm[3];
        const double St0 = sm[4], St1 = sm[5], St2 = sm[6];
        const double pc0 = Sp0 / Mep, pc1 = Sp1 / Mep, pc2 = Sp2 / Mep;
        const double tc0 = St0 / Mep, tc1 = St1 / Mep, tc2 = St2 / Mep;
        const double Qp = sm[7], Qt = sm[8];

        const double Sxx = sm[9]  - pc0 * St0 - tc0 * Sp0 + pc0 * tc0 * M;
        const double Sxy = sm[10] - pc0 * St1 - tc1 * Sp0 + pc0 * tc1 * M;
        const double Sxz = sm[11] - pc0 * St2 - tc2 * Sp0 + pc0 * tc2 * M;
        const double Syx = sm[12] - pc1 * St0 - tc0 * Sp1 + pc1 * tc0 * M;
        const double Syy = sm[13] - pc1 * St1 - tc1 * Sp1 + pc1 * tc1 * M;
        const double Syz = sm[14] - pc1 * St2 - tc2 * Sp1 + pc1 * tc2 * M;
        const double Szx = sm[15] - pc2 * St0 - tc0 * Sp2 + pc2 * tc0 * M;
        const double Szy = sm[16] - pc2 * St1 - tc1 * Sp2 + pc2 * tc1 * M;
        const double Szz = sm[17] - pc2 * St2 - tc2 * Sp2 + pc2 * tc2 * M;

        const double Qpc = Qp - 2.0*(pc0*Sp0 + pc1*Sp1 + pc2*Sp2)
                         + (pc0*pc0 + pc1*pc1 + pc2*pc2) * M;
        const double Qtc = Qt - 2.0*(tc0*St0 + tc1*St1 + tc2*St2)
                         + (tc0*tc0 + tc1*tc1 + tc2*tc2) * M;

        // ---- QCP characteristic quartic: x^4 + C2 x^2 + C1 x + C0 ----
        const double Sxx2 = Sxx*Sxx, Syy2 = Syy*Syy, Szz2 = Szz*Szz;
        const double Sxy2 = Sxy*Sxy, Syz2 = Syz*Syz, Sxz2 = Sxz*Sxz;
        const double Syx2 = Syx*Syx, Szy2 = Szy*Szy, Szx2 = Szx*Szx;

        const double SyzSzymSyySzz2 = 2.0*(Syz*Szy - Syy*Szz);
        const double Sxx2Syy2Szz2Syz2Szy2 = Syy2 + Szz2 - Sxx2 + Syz2 + Szy2;

        const double C2 = -2.0*(Sxx2 + Syy2 + Szz2 + Sxy2 + Syx2 + Sxz2 + Szx2 + Syz2 + Szy2);
        const double C1 = 8.0*(Sxx*Syz*Szy + Syy*Szx*Sxz + Szz*Sxy*Syx
                             - Sxx*Syy*Szz - Syz*Szx*Sxy - Szy*Syx*Sxz);

        const double SxzpSzx = Sxz + Szx;
        const double SyzpSzy = Syz + Szy;
        const double SxypSyx = Sxy + Syx;
        const double SyzmSzy = Syz - Szy;
        const double SxzmSzx = Sxz - Szx;
        const double SxymSyx = Sxy - Syx;
        const double SxxpSyy = Sxx + Syy;
        const double SxxmSyy = Sxx - Syy;
        const double Sxy2Sxz2Syx2Szx2 = Sxy2 + Sxz2 - Syx2 - Szx2;

        const double C0 =
            Sxy2Sxz2Syx2Szx2 * Sxy2Sxz2Syx2Szx2
          + (Sxx2Syy2Szz2Syz2Szy2 + SyzSzymSyySzz2) * (Sxx2Syy2Szz2Syz2Szy2 - SyzSzymSyySzz2)
          + (-(SxzpSzx)*(SyzmSzy) + (SxymSyx)*(SxxmSyy - Szz)) *
            (-(SxzmSzx)*(SyzpSzy) + (SxymSyx)*(SxxmSyy + Szz))
          + (-(SxzpSzx)*(SyzpSzy) - (SxypSyx)*(SxxpSyy - Szz)) *
            (-(SxzmSzx)*(SyzmSzy) - (SxypSyx)*(SxxpSyy + Szz))
          + ( (SxypSyx)*(SyzpSzy) + (SxzpSzx)*(SxxmSyy + Szz)) *
            (-(SxymSyx)*(SyzmSzy) + (SxzpSzx)*(SxxpSyy + Szz))
          + ( (SxypSyx)*(SyzmSzy) + (SxzmSzx)*(SxxmSyy - Szz)) *
            (-(SxymSyx)*(SyzpSzy) + (SxzmSzx)*(SxxpSyy - Szz));

        // Newton from above: lambda0 = (Qpc+Qtc)/2 >= lambda_max.
        double lam = 0.5 * (Qpc + Qtc);
#pragma unroll
        for (int it = 0; it < 16; ++it) {
            const double x2 = lam * lam;
            const double bq = (x2 + C2) * lam;
            const double aq = bq + C1;
            const double den = 2.0 * x2 * lam + bq + aq;
            const double num = aq * lam + C0;
            const double d = (fabs(den) > 1e-300) ? (num / den) : 0.0;
            lam -= d;
        }

        double D = Qpc + Qtc - 2.0 * lam;
        if (D < 0.0) D = 0.0;
        float rmsd = (float)sqrt(D / Mep);

        // mean over 256 batches: only waves 0..3 hold real batches
#pragma unroll
        for (int off = 32; off > 0; off >>= 1) rmsd += __shfl_down(rmsd, off, 64);
        __shared__ float part[4];
        if ((tid & 63) == 0 && (tid >> 6) < 4) part[tid >> 6] = rmsd;
        __syncthreads();
        if (tid == 0)
            out[0] = (part[0] + part[1] + part[2] + part[3]) * (1.0f / (float)NBATCH);
    }
}

extern "C" void kernel_launch(void* const* d_in, const int* in_sizes, int n_in,
                              void* d_out, int out_size, void* d_ws, size_t ws_size,
                              hipStream_t stream) {
    const float* pred  = (const float*)d_in[0];
    const float* truec = (const float*)d_in[1];
    const float* mask  = (const float*)d_in[2];
    float* out = (float*)d_out;
    float* partials = (float*)d_ws;                       // 1024*18 floats = 73728 B
    unsigned int* ticket = (unsigned int*)((char*)d_ws + BLOCKS * NSUM * sizeof(float));

    // Graph-capturable (memset node); guarantees ticket==0 on every replay.
    hipMemsetAsync(ticket, 0, sizeof(unsigned int), stream);
    rmsd_fused_kernel<<<BLOCKS, 512, 0, stream>>>(
        pred, truec, mask, partials, ticket, out);
}

// Round 5
// 369.420 us; speedup vs baseline: 1.2446x; 1.2446x over previous
//
#include <hip/hip_runtime.h>
#include <math.h>

#define N_RES 1024
#define N_ATOMS 37
#define ATOM_CA 1
#define NBATCH 256
#define BLOCKS 1024           // 4 per batch, 256 threads, 1 residue/thread
#define SLICES 4              // partial rows per batch
#define NSUM 18
// Empirical ranking (rounds 2-4, identical FETCH_SIZE ~51 MB):
//   1 res/thread simple scatter  ~55-65us   (prev session pass-1)
//   2 res/thread                 100us      (round 2)
//   LDS barrier-stream           205us      (round 3: 2.6x bytes @ 0.66 TB/s)
//   paired half-res + VGPR=32    290us      (round 4; occupancy 14%..66% all
//                                            equally slow -> NOT wave-bound)
// The scatter is DRAM-row-locality bound: contiguous per-wave windows with
// few, independent, unsqueezed loads win. This file = best config + fused
// ticket finish (verified absmax 0.0).
//
// sums layout per partial row:
// 0: M    1-3: Sp    4-6: St    7: Qp    8: Qt    9-17: Cpt[i][j]
// Workspace: float partials[1024][18] (73728 B), then uint ticket (4 B).

// 12-byte triple -> single global_load_dwordx3.
struct F3 { float x, y, z; };

__global__ __launch_bounds__(256) void rmsd_fused_kernel(
    const float* __restrict__ pred, const float* __restrict__ truec,
    const float* __restrict__ mask, float* __restrict__ partials,
    unsigned int* __restrict__ ticket, float* __restrict__ out)
{
    const int blk = blockIdx.x;        // 0..1023
    const int b   = blk >> 2;          // batch
    const int s   = blk & 3;           // tile-of-256 residues
    const int tid = threadIdx.x;       // 0..255
    const int n   = s * 256 + tid;     // residue

    const size_t r = (size_t)b * N_RES + n;
    const float* pp = pred  + r * (N_ATOMS * 3) + ATOM_CA * 3;
    const float* tt = truec + r * (N_ATOMS * 3) + ATOM_CA * 3;

    // Three independent loads, issued back-to-back (they ARE the kernel).
    const F3 P = *reinterpret_cast<const F3*>(pp);
    const F3 T = *reinterpret_cast<const F3*>(tt);
    const float m = mask[r * N_ATOMS + ATOM_CA];

    const float p0 = P.x, p1 = P.y, p2 = P.z;
    const float t0 = T.x, t1 = T.y, t2 = T.z;

    // ---- per-thread moments (binary mask => m^2 == m) ----
    float acc[NSUM];
    acc[0] = m;
    acc[1] = m * p0;  acc[2] = m * p1;  acc[3] = m * p2;
    acc[4] = m * t0;  acc[5] = m * t1;  acc[6] = m * t2;
    acc[7] = m * (p0*p0 + p1*p1 + p2*p2);
    acc[8] = m * (t0*t0 + t1*t1 + t2*t2);
    acc[9]  = m * p0 * t0; acc[10] = m * p0 * t1; acc[11] = m * p0 * t2;
    acc[12] = m * p1 * t0; acc[13] = m * p1 * t1; acc[14] = m * p1 * t2;
    acc[15] = m * p2 * t0; acc[16] = m * p2 * t1; acc[17] = m * p2 * t2;

    // wave(64) shuffle reduce
#pragma unroll
    for (int k = 0; k < NSUM; ++k) {
        float v = acc[k];
#pragma unroll
        for (int off = 32; off > 0; off >>= 1) v += __shfl_down(v, off, 64);
        acc[k] = v;
    }

    __shared__ float partial[4][NSUM];
    const int wave = tid >> 6, lane = tid & 63;
    if (lane == 0) {
#pragma unroll
        for (int k = 0; k < NSUM; ++k) partial[wave][k] = acc[k];
    }
    __syncthreads();
    if (tid < NSUM) {
        partials[(size_t)blk * NSUM + tid] =
            partial[0][tid] + partial[1][tid] + partial[2][tid] + partial[3][tid];
    }

    // ---- last-block-done handoff (device-scope, XCD-safe) ----
    __threadfence();
    __syncthreads();
    __shared__ bool amLast;
    if (tid == 0)
        amLast = (atomicAdd(ticket, 1u) == (unsigned)(gridDim.x - 1));
    __syncthreads();
    if (!amLast) return;
    __threadfence();

    // ---- finish: thread b = batch b. Theobald QCP, fp64, register-only ----
    {
        const int bb = tid;
        double sm[NSUM];
#pragma unroll
        for (int k = 0; k < NSUM; ++k) sm[k] = 0.0;
#pragma unroll
        for (int k = 0; k < SLICES; ++k) {
            const float* row = partials + ((size_t)bb * SLICES + k) * NSUM;
#pragma unroll
            for (int j = 0; j < NSUM; ++j) sm[j] += (double)row[j];
        }

        const double M   = sm[0];
        const double Mep = M + 1e-8;
        const double Sp0 = sm[1], Sp1 = sm[2], Sp2 = sm[3];
        const double St0 = sm[4], St1 = sm[5], St2 = sm[6];
        const double pc0 = Sp0 / Mep, pc1 = Sp1 / Mep, pc2 = Sp2 / Mep;
        const double tc0 = St0 / Mep, tc1 = St1 / Mep, tc2 = St2 / Mep;
        const double Qp = sm[7], Qt = sm[8];

        const double Sxx = sm[9]  - pc0 * St0 - tc0 * Sp0 + pc0 * tc0 * M;
        const double Sxy = sm[10] - pc0 * St1 - tc1 * Sp0 + pc0 * tc1 * M;
        const double Sxz = sm[11] - pc0 * St2 - tc2 * Sp0 + pc0 * tc2 * M;
        const double Syx = sm[12] - pc1 * St0 - tc0 * Sp1 + pc1 * tc0 * M;
        const double Syy = sm[13] - pc1 * St1 - tc1 * Sp1 + pc1 * tc1 * M;
        const double Syz = sm[14] - pc1 * St2 - tc2 * Sp1 + pc1 * tc2 * M;
        const double Szx = sm[15] - pc2 * St0 - tc0 * Sp2 + pc2 * tc0 * M;
        const double Szy = sm[16] - pc2 * St1 - tc1 * Sp2 + pc2 * tc1 * M;
        const double Szz = sm[17] - pc2 * St2 - tc2 * Sp2 + pc2 * tc2 * M;

        const double Qpc = Qp - 2.0*(pc0*Sp0 + pc1*Sp1 + pc2*Sp2)
                         + (pc0*pc0 + pc1*pc1 + pc2*pc2) * M;
        const double Qtc = Qt - 2.0*(tc0*St0 + tc1*St1 + tc2*St2)
                         + (tc0*tc0 + tc1*tc1 + tc2*tc2) * M;

        // ---- QCP characteristic quartic: x^4 + C2 x^2 + C1 x + C0 ----
        const double Sxx2 = Sxx*Sxx, Syy2 = Syy*Syy, Szz2 = Szz*Szz;
        const double Sxy2 = Sxy*Sxy, Syz2 = Syz*Syz, Sxz2 = Sxz*Sxz;
        const double Syx2 = Syx*Syx, Szy2 = Szy*Szy, Szx2 = Szx*Szx;

        const double SyzSzymSyySzz2 = 2.0*(Syz*Szy - Syy*Szz);
        const double Sxx2Syy2Szz2Syz2Szy2 = Syy2 + Szz2 - Sxx2 + Syz2 + Szy2;

        const double C2 = -2.0*(Sxx2 + Syy2 + Szz2 + Sxy2 + Syx2 + Sxz2 + Szx2 + Syz2 + Szy2);
        const double C1 = 8.0*(Sxx*Syz*Szy + Syy*Szx*Sxz + Szz*Sxy*Syx
                             - Sxx*Syy*Szz - Syz*Szx*Sxy - Szy*Syx*Sxz);

        const double SxzpSzx = Sxz + Szx;
        const double SyzpSzy = Syz + Szy;
        const double SxypSyx = Sxy + Syx;
        const double SyzmSzy = Syz - Szy;
        const double SxzmSzx = Sxz - Szx;
        const double SxymSyx = Sxy - Syx;
        const double SxxpSyy = Sxx + Syy;
        const double SxxmSyy = Sxx - Syy;
        const double Sxy2Sxz2Syx2Szx2 = Sxy2 + Sxz2 - Syx2 - Szx2;

        const double C0 =
            Sxy2Sxz2Syx2Szx2 * Sxy2Sxz2Syx2Szx2
          + (Sxx2Syy2Szz2Syz2Szy2 + SyzSzymSyySzz2) * (Sxx2Syy2Szz2Syz2Szy2 - SyzSzymSyySzz2)
          + (-(SxzpSzx)*(SyzmSzy) + (SxymSyx)*(SxxmSyy - Szz)) *
            (-(SxzmSzx)*(SyzpSzy) + (SxymSyx)*(SxxmSyy + Szz))
          + (-(SxzpSzx)*(SyzpSzy) - (SxypSyx)*(SxxpSyy - Szz)) *
            (-(SxzmSzx)*(SyzmSzy) - (SxypSyx)*(SxxpSyy + Szz))
          + ( (SxypSyx)*(SyzpSzy) + (SxzpSzx)*(SxxmSyy + Szz)) *
            (-(SxymSyx)*(SyzmSzy) + (SxzpSzx)*(SxxpSyy + Szz))
          + ( (SxypSyx)*(SyzmSzy) + (SxzmSzx)*(SxxmSyy - Szz)) *
            (-(SxymSyx)*(SyzpSzy) + (SxzmSzx)*(SxxpSyy - Szz));

        // Newton from above: lambda0 = (Qpc+Qtc)/2 >= lambda_max.
        double lam = 0.5 * (Qpc + Qtc);
#pragma unroll
        for (int it = 0; it < 16; ++it) {
            const double x2 = lam * lam;
            const double bq = (x2 + C2) * lam;
            const double aq = bq + C1;
            const double den = 2.0 * x2 * lam + bq + aq;
            const double num = aq * lam + C0;
            const double d = (fabs(den) > 1e-300) ? (num / den) : 0.0;
            lam -= d;
        }

        double D = Qpc + Qtc - 2.0 * lam;
        if (D < 0.0) D = 0.0;
        float rmsd = (float)sqrt(D / Mep);

        // mean over 256 batches
#pragma unroll
        for (int off = 32; off > 0; off >>= 1) rmsd += __shfl_down(rmsd, off, 64);
        __shared__ float part[4];
        if ((tid & 63) == 0) part[tid >> 6] = rmsd;
        __syncthreads();
        if (tid == 0)
            out[0] = (part[0] + part[1] + part[2] + part[3]) * (1.0f / (float)NBATCH);
    }
}

extern "C" void kernel_launch(void* const* d_in, const int* in_sizes, int n_in,
                              void* d_out, int out_size, void* d_ws, size_t ws_size,
                              hipStream_t stream) {
    const float* pred  = (const float*)d_in[0];
    const float* truec = (const float*)d_in[1];
    const float* mask  = (const float*)d_in[2];
    float* out = (float*)d_out;
    float* partials = (float*)d_ws;                       // 1024*18 floats = 73728 B
    unsigned int* ticket = (unsigned int*)((char*)d_ws + BLOCKS * NSUM * sizeof(float));

    // Graph-capturable (memset node); guarantees ticket==0 on every replay.
    hipMemsetAsync(ticket, 0, sizeof(unsigned int), stream);
    rmsd_fused_kernel<<<BLOCKS, 256, 0, stream>>>(
        pred, truec, mask, partials, ticket, out);
}

// Round 7
// 241.324 us; speedup vs baseline: 1.9052x; 1.5308x over previous
//
#include <hip/hip_runtime.h>
#include <math.h>

#define N_RES 1024
#define N_ATOMS 37
#define ATOM_CA 1
#define NBATCH 256
#define BLOCKS 1024           // 4 per batch, 256 threads, 1 residue/thread
#define SLICES 4              // partial rows per batch
#define NSUM 18
// ROUND-5 DIAGNOSIS: L3-resident replays run at IDENTICAL speed to
// HBM-fetching ones -> scatter is on-chip request-path-bound, not DRAM-bound.
// Fused-kernel times fit t = ~55us + ~28ns * (#waves * __threadfence())
// (device-scope fence = L2 writeback, XCDs non-coherent, serializes at TCC).
// FIX: two dispatches, ZERO fences. Mask dedup: coalesced float4 -> LDS.
// ROUND-6 BUG (fixed here): mask span per 256-residue block is 256*37
// floats = 2368 float4 = 37888 B, NOT 592 float4 (that was the 64-residue
// quarter from round 3). Round 6 staged 1/4 of the masks -> OOB LDS reads.
//
// sums layout per partial row:
// 0: M    1-3: Sp    4-6: St    7: Qp    8: Qt    9-17: Cpt[i][j]
// Workspace: float partials[1024][18] = 73728 B.

// 12-byte triple -> single global_load_dwordx3.
struct F3 { float x, y, z; };

#define MQ_F4 2368            // 256 residues * 37 floats = 9472 floats = 2368 float4

__global__ __launch_bounds__(256) void rmsd_moments_kernel(
    const float* __restrict__ pred, const float* __restrict__ truec,
    const float* __restrict__ mask, float* __restrict__ partials)
{
    const int blk = blockIdx.x;        // 0..1023
    const int b   = blk >> 2;          // batch
    const int s   = blk & 3;           // tile-of-256 residues
    const int tid = threadIdx.x;       // 0..255
    const int n   = s * 256 + tid;     // residue

    const size_t r = (size_t)b * N_RES + n;
    const float* pp = pred  + r * (N_ATOMS * 3) + ATOM_CA * 3;
    const float* tt = truec + r * (N_ATOMS * 3) + ATOM_CA * 3;

    // Scattered coord loads issued FIRST -> in flight across the mask phase.
    const F3 P = *reinterpret_cast<const F3*>(pp);
    const F3 T = *reinterpret_cast<const F3*>(tt);

    // Cooperative coalesced mask fetch: block's 256 residues span 2368
    // float4 starting at resBase*37 floats (byte base resBase*148, and
    // resBase % 256 == 0 -> 16B-aligned).
    __shared__ __align__(16) float mbuf[MQ_F4 * 4];
    {
        const size_t resBase = (size_t)b * N_RES + s * 256;
        const float4* msrc = reinterpret_cast<const float4*>(mask + resBase * N_ATOMS);
        float4* mdst = reinterpret_cast<float4*>(mbuf);
        for (int idx = tid; idx < MQ_F4; idx += 256) mdst[idx] = msrc[idx];
    }
    __syncthreads();
    const float m = mbuf[tid * N_ATOMS + ATOM_CA];  // bank (5*tid+1)%32: 2-way, free

    const float p0 = P.x, p1 = P.y, p2 = P.z;
    const float t0 = T.x, t1 = T.y, t2 = T.z;

    // ---- per-thread moments (binary mask => m^2 == m) ----
    float acc[NSUM];
    acc[0] = m;
    acc[1] = m * p0;  acc[2] = m * p1;  acc[3] = m * p2;
    acc[4] = m * t0;  acc[5] = m * t1;  acc[6] = m * t2;
    acc[7] = m * (p0*p0 + p1*p1 + p2*p2);
    acc[8] = m * (t0*t0 + t1*t1 + t2*t2);
    acc[9]  = m * p0 * t0; acc[10] = m * p0 * t1; acc[11] = m * p0 * t2;
    acc[12] = m * p1 * t0; acc[13] = m * p1 * t1; acc[14] = m * p1 * t2;
    acc[15] = m * p2 * t0; acc[16] = m * p2 * t1; acc[17] = m * p2 * t2;

    // wave(64) shuffle reduce
#pragma unroll
    for (int k = 0; k < NSUM; ++k) {
        float v = acc[k];
#pragma unroll
        for (int off = 32; off > 0; off >>= 1) v += __shfl_down(v, off, 64);
        acc[k] = v;
    }

    __shared__ float partial[4][NSUM];
    const int wave = tid >> 6, lane = tid & 63;
    if (lane == 0) {
#pragma unroll
        for (int k = 0; k < NSUM; ++k) partial[wave][k] = acc[k];
    }
    __syncthreads();
    if (tid < NSUM) {
        partials[(size_t)blk * NSUM + tid] =
            partial[0][tid] + partial[1][tid] + partial[2][tid] + partial[3][tid];
    }
}

// Pass 2: one block, 256 threads; thread b = batch b. Theobald QCP in fp64,
// register-only (dynamic indexing would be demoted to scratch).
__global__ __launch_bounds__(256) void rmsd_finish_kernel(
    const float* __restrict__ partials, float* __restrict__ out)
{
    const int bb = threadIdx.x;

    double sm[NSUM];
#pragma unroll
    for (int k = 0; k < NSUM; ++k) sm[k] = 0.0;
#pragma unroll
    for (int k = 0; k < SLICES; ++k) {
        const float* row = partials + ((size_t)bb * SLICES + k) * NSUM;
#pragma unroll
        for (int j = 0; j < NSUM; ++j) sm[j] += (double)row[j];
    }

    const double M   = sm[0];
    const double Mep = M + 1e-8;
    const double Sp0 = sm[1], Sp1 = sm[2], Sp2 = sm[3];
    const double St0 = sm[4], St1 = sm[5], St2 = sm[6];
    const double pc0 = Sp0 / Mep, pc1 = Sp1 / Mep, pc2 = Sp2 / Mep;
    const double tc0 = St0 / Mep, tc1 = St1 / Mep, tc2 = St2 / Mep;
    const double Qp = sm[7], Qt = sm[8];

    const double Sxx = sm[9]  - pc0 * St0 - tc0 * Sp0 + pc0 * tc0 * M;
    const double Sxy = sm[10] - pc0 * St1 - tc1 * Sp0 + pc0 * tc1 * M;
    const double Sxz = sm[11] - pc0 * St2 - tc2 * Sp0 + pc0 * tc2 * M;
    const double Syx = sm[12] - pc1 * St0 - tc0 * Sp1 + pc1 * tc0 * M;
    const double Syy = sm[13] - pc1 * St1 - tc1 * Sp1 + pc1 * tc1 * M;
    const double Syz = sm[14] - pc1 * St2 - tc2 * Sp1 + pc1 * tc2 * M;
    const double Szx = sm[15] - pc2 * St0 - tc0 * Sp2 + pc2 * tc0 * M;
    const double Szy = sm[16] - pc2 * St1 - tc1 * Sp2 + pc2 * tc1 * M;
    const double Szz = sm[17] - pc2 * St2 - tc2 * Sp2 + pc2 * tc2 * M;

    const double Qpc = Qp - 2.0*(pc0*Sp0 + pc1*Sp1 + pc2*Sp2)
                     + (pc0*pc0 + pc1*pc1 + pc2*pc2) * M;
    const double Qtc = Qt - 2.0*(tc0*St0 + tc1*St1 + tc2*St2)
                     + (tc0*tc0 + tc1*tc1 + tc2*tc2) * M;

    // ---- QCP characteristic quartic: x^4 + C2 x^2 + C1 x + C0 ----
    const double Sxx2 = Sxx*Sxx, Syy2 = Syy*Syy, Szz2 = Szz*Szz;
    const double Sxy2 = Sxy*Sxy, Syz2 = Syz*Syz, Sxz2 = Sxz*Sxz;
    const double Syx2 = Syx*Syx, Szy2 = Szy*Szy, Szx2 = Szx*Szx;

    const double SyzSzymSyySzz2 = 2.0*(Syz*Szy - Syy*Szz);
    const double Sxx2Syy2Szz2Syz2Szy2 = Syy2 + Szz2 - Sxx2 + Syz2 + Szy2;

    const double C2 = -2.0*(Sxx2 + Syy2 + Szz2 + Sxy2 + Syx2 + Sxz2 + Szx2 + Syz2 + Szy2);
    const double C1 = 8.0*(Sxx*Syz*Szy + Syy*Szx*Sxz + Szz*Sxy*Syx
                         - Sxx*Syy*Szz - Syz*Szx*Sxy - Szy*Syx*Sxz);

    const double SxzpSzx = Sxz + Szx;
    const double SyzpSzy = Syz + Szy;
    const double SxypSyx = Sxy + Syx;
    const double SyzmSzy = Syz - Szy;
    const double SxzmSzx = Sxz - Szx;
    const double SxymSyx = Sxy - Syx;
    const double SxxpSyy = Sxx + Syy;
    const double SxxmSyy = Sxx - Syy;
    const double Sxy2Sxz2Syx2Szx2 = Sxy2 + Sxz2 - Syx2 - Szx2;

    const double C0 =
        Sxy2Sxz2Syx2Szx2 * Sxy2Sxz2Syx2Szx2
      + (Sxx2Syy2Szz2Syz2Szy2 + SyzSzymSyySzz2) * (Sxx2Syy2Szz2Syz2Szy2 - SyzSzymSyySzz2)
      + (-(SxzpSzx)*(SyzmSzy) + (SxymSyx)*(SxxmSyy - Szz)) *
        (-(SxzmSzx)*(SyzpSzy) + (SxymSyx)*(SxxmSyy + Szz))
      + (-(SxzpSzx)*(SyzpSzy) - (SxypSyx)*(SxxpSyy - Szz)) *
        (-(SxzmSzx)*(SyzmSzy) - (SxypSyx)*(SxxpSyy + Szz))
      + ( (SxypSyx)*(SyzpSzy) + (SxzpSzx)*(SxxmSyy + Szz)) *
        (-(SxymSyx)*(SyzmSzy) + (SxzpSzx)*(SxxpSyy + Szz))
      + ( (SxypSyx)*(SyzmSzy) + (SxzmSzx)*(SxxmSyy - Szz)) *
        (-(SxymSyx)*(SyzpSzy) + (SxzmSzx)*(SxxpSyy - Szz));

    // Newton from above: lambda0 = (Qpc+Qtc)/2 >= lambda_max.
    double lam = 0.5 * (Qpc + Qtc);
#pragma unroll
    for (int it = 0; it < 16; ++it) {
        const double x2 = lam * lam;
        const double bq = (x2 + C2) * lam;
        const double aq = bq + C1;
        const double den = 2.0 * x2 * lam + bq + aq;
        const double num = aq * lam + C0;
        const double d = (fabs(den) > 1e-300) ? (num / den) : 0.0;
        lam -= d;
    }

    double D = Qpc + Qtc - 2.0 * lam;
    if (D < 0.0) D = 0.0;
    float rmsd = (float)sqrt(D / Mep);

    // mean over 256 batches
#pragma unroll
    for (int off = 32; off > 0; off >>= 1) rmsd += __shfl_down(rmsd, off, 64);
    __shared__ float part[4];
    if ((threadIdx.x & 63) == 0) part[threadIdx.x >> 6] = rmsd;
    __syncthreads();
    if (threadIdx.x == 0)
        out[0] = (part[0] + part[1] + part[2] + part[3]) * (1.0f / (float)NBATCH);
}

extern "C" void kernel_launch(void* const* d_in, const int* in_sizes, int n_in,
                              void* d_out, int out_size, void* d_ws, size_t ws_size,
                              hipStream_t stream) {
    const float* pred  = (const float*)d_in[0];
    const float* truec = (const float*)d_in[1];
    const float* mask  = (const float*)d_in[2];
    float* out = (float*)d_out;
    float* partials = (float*)d_ws;   // 1024 * 18 floats = 73728 B

    rmsd_moments_kernel<<<BLOCKS, 256, 0, stream>>>(pred, truec, mask, partials);
    rmsd_finish_kernel<<<1, 256, 0, stream>>>(partials, out);
}